// Round 1
// baseline (306.271 us; speedup 1.0000x reference)
//
#include <hip/hip_runtime.h>

#define B_ 16
#define D_ 128
#define L_ 8192
#define M_ 128
#define LT 512
#define NCHUNK 16
#define SL 64
#define PHI_SCALE 0.08838834764831845f

typedef unsigned short ushort_t;
typedef ushort_t ushort8 __attribute__((ext_vector_type(8)));
typedef ushort_t ushort4v __attribute__((ext_vector_type(4)));
typedef float float4v __attribute__((ext_vector_type(4)));
typedef __bf16 bf16x8 __attribute__((ext_vector_type(8)));

__device__ __forceinline__ ushort_t f2bf(float f) {
    unsigned int u = __builtin_bit_cast(unsigned int, f);
    unsigned int r = u + 0x7FFFu + ((u >> 16) & 1u);   // RTNE
    return (ushort_t)(r >> 16);
}

__device__ __forceinline__ float4v mfma16(ushort8 a, ushort8 b, float4v c) {
    return __builtin_amdgcn_mfma_f32_16x16x32_bf16(
        __builtin_bit_cast(bf16x8, a), __builtin_bit_cast(bf16x8, b), c, 0, 0, 0);
}

// Stage F (D x M) into LDS as GEMM B-fragment layout: blocks [kt 0..3][nt 0..7][lane64][j 0..7]
// B[k=d][n=m], lane = qb*16+cb -> k = kt*32+qb*8+j, m = nt*16+cb
__device__ __forceinline__ void stage_features(const float* __restrict__ features,
                                               ushort_t* FB, int tid) {
#pragma unroll
    for (int it = 0; it < 8; ++it) {
        int bid = tid + it * 256;            // 0..2047
        int cb = bid & 15;
        int qb = (bid >> 4) & 3;
        int nt = (bid >> 6) & 7;
        int kt = bid >> 9;
        int m  = nt * 16 + cb;
        int d0 = kt * 32 + qb * 8;
        const float* fp = features + d0 * M_ + m;
        ushort8 u;
#pragma unroll
        for (int j = 0; j < 8; ++j) u[j] = f2bf(fp[j * M_]);
        *(ushort8*)(FB + bid * 8) = u;
    }
}

// Kernel A: per (chunk,b): phi_k = relu(K^T F)*s ; kv_part[m][v] += phi^T V^T ; ksum partials
__global__ __launch_bounds__(256) void kernelA(const float* __restrict__ keys,
                                               const float* __restrict__ values,
                                               const float* __restrict__ features,
                                               float* __restrict__ kvp,
                                               float* __restrict__ ksum_p) {
    __shared__ ushort_t FB[16384];  // 32 KB : F B-frags
    __shared__ ushort_t PA[8192];   // 16 KB : phi^T A-frags (64 l x 128 m)
    __shared__ ushort_t VB[8192];   // 16 KB : V B-frags   (64 l x 128 v)

    const int tid = threadIdx.x;
    const int chunk = blockIdx.x, b = blockIdx.y;
    const int w = tid >> 6, lane = tid & 63;
    const int qa = lane >> 4, ra = lane & 15;

    stage_features(features, FB, tid);

    float4v acc2[2][8];
    float   ksum_acc[8];
#pragma unroll
    for (int i = 0; i < 2; ++i)
#pragma unroll
        for (int nt = 0; nt < 8; ++nt) acc2[i][nt] = (float4v){0.f, 0.f, 0.f, 0.f};
#pragma unroll
    for (int nt = 0; nt < 8; ++nt) ksum_acc[nt] = 0.f;

    const int l0 = chunk * LT;

    for (int s = 0; s < 8; ++s) {
        const int ls = l0 + s * SL;
        __syncthreads();  // prev GEMM2 done; PA/VB reusable; (s=0: FB visible)

        // ---- stage V subtile into B-frag layout: B[k=l_rel][n=v]
#pragma unroll
        for (int it = 0; it < 4; ++it) {
            int bid = tid + it * 256;        // 0..1023
            int cb = bid & 15;
            int qb = (bid >> 4) & 3;
            int nt = (bid >> 6) & 7;
            int kt = bid >> 9;               // 0..1
            int v  = nt * 16 + cb;
            int lr = kt * 32 + qb * 8;
            const float* vp = values + ((size_t)(b * D_ + v)) * L_ + ls + lr;
            float4v f0 = *(const float4v*)vp;
            float4v f1 = *(const float4v*)(vp + 4);
            ushort8 u;
            u[0] = f2bf(f0.x); u[1] = f2bf(f0.y); u[2] = f2bf(f0.z); u[3] = f2bf(f0.w);
            u[4] = f2bf(f1.x); u[5] = f2bf(f1.y); u[6] = f2bf(f1.z); u[7] = f2bf(f1.w);
            *(ushort8*)(VB + bid * 8) = u;
        }

        // ---- GEMM1: phi(64 x 128) = K_sub^T (64 x 128) @ F(128 x 128); wave w owns l-rows [w*16, w*16+16)
        float4v acc1[8];
#pragma unroll
        for (int nt = 0; nt < 8; ++nt) acc1[nt] = (float4v){0.f, 0.f, 0.f, 0.f};
        const int l = ls + w * 16 + ra;
#pragma unroll
        for (int kt = 0; kt < 4; ++kt) {
            const float* kp = keys + ((size_t)(b * D_ + kt * 32 + qa * 8)) * L_ + l;
            ushort8 a;
#pragma unroll
            for (int j = 0; j < 8; ++j) a[j] = f2bf(kp[(size_t)j * L_]);
#pragma unroll
            for (int nt = 0; nt < 8; ++nt)
                acc1[nt] = mfma16(a, *(const ushort8*)(FB + ((kt * 8 + nt) * 64 + lane) * 8),
                                  acc1[nt]);
        }

        // ---- epilogue: relu*scale, ksum accumulate, write phi^T into A-frag layout (b64 packed)
        {
            const int qc = qa, cc = ra;
            const int kt2 = w >> 1;
            const int qa2 = (w & 1) * 2 + (qc >> 1);
            const int jb  = (qc & 1) * 4;
#pragma unroll
            for (int nt = 0; nt < 8; ++nt) {
                float4v p = acc1[nt];
                p.x = fmaxf(p.x, 0.f) * PHI_SCALE;
                p.y = fmaxf(p.y, 0.f) * PHI_SCALE;
                p.z = fmaxf(p.z, 0.f) * PHI_SCALE;
                p.w = fmaxf(p.w, 0.f) * PHI_SCALE;
                ksum_acc[nt] += p.x + p.y + p.z + p.w;
                ushort4v u4 = {f2bf(p.x), f2bf(p.y), f2bf(p.z), f2bf(p.w)};
                *(ushort4v*)(PA + (((kt2 * 8 + nt) * 64 + qa2 * 16 + cc) * 8 + jb)) = u4;
            }
        }
        __syncthreads();  // PA + VB visible

        // ---- GEMM2: kv[m][v] += phi^T (128 x 64) @ V (64 x 128); wave w owns m-rows [32w,32w+32)
#pragma unroll
        for (int kt2 = 0; kt2 < 2; ++kt2) {
            ushort8 a0 = *(const ushort8*)(PA + ((kt2 * 8 + 2 * w + 0) * 64 + lane) * 8);
            ushort8 a1 = *(const ushort8*)(PA + ((kt2 * 8 + 2 * w + 1) * 64 + lane) * 8);
#pragma unroll
            for (int nt = 0; nt < 8; ++nt) {
                ushort8 bb = *(const ushort8*)(VB + ((kt2 * 8 + nt) * 64 + lane) * 8);
                acc2[0][nt] = mfma16(a0, bb, acc2[0][nt]);
                acc2[1][nt] = mfma16(a1, bb, acc2[1][nt]);
            }
        }
    }

    // ---- write kv partials (f32) and ksum partials
    float* kvpb = kvp + ((size_t)(b * NCHUNK + chunk)) * M_ * D_;
    const int qc = lane >> 4, cc = lane & 15;
#pragma unroll
    for (int mi = 0; mi < 2; ++mi)
#pragma unroll
        for (int nt = 0; nt < 8; ++nt) {
            float4v p = acc2[mi][nt];
            int m0 = w * 32 + mi * 16 + qc * 4;
            int v  = nt * 16 + cc;
            kvpb[(m0 + 0) * D_ + v] = p.x;
            kvpb[(m0 + 1) * D_ + v] = p.y;
            kvpb[(m0 + 2) * D_ + v] = p.z;
            kvpb[(m0 + 3) * D_ + v] = p.w;
        }
    float* ksb = ksum_p + ((size_t)((b * NCHUNK + chunk) * 4 + w)) * M_;
#pragma unroll
    for (int nt = 0; nt < 8; ++nt) {
        float sv = ksum_acc[nt];
        sv += __shfl_xor(sv, 16);
        sv += __shfl_xor(sv, 32);
        if (qc == 0) ksb[nt * 16 + cc] = sv;  // m = nt*16+cc, summed over this wave's 16 l
    }
}

// Kernel Q: phi_q = relu(Q^T F)*s  -> global bf16, (l,m) row-major
__global__ __launch_bounds__(256) void kernelQ(const float* __restrict__ queries,
                                               const float* __restrict__ features,
                                               ushort_t* __restrict__ phi_q) {
    __shared__ ushort_t FB[16384];
    const int tid = threadIdx.x;
    const int chunk = blockIdx.x, b = blockIdx.y;
    const int w = tid >> 6, lane = tid & 63;
    const int qa = lane >> 4, ra = lane & 15;

    stage_features(features, FB, tid);
    __syncthreads();

    const int l0 = chunk * LT;
    for (int s = 0; s < 8; ++s) {
        const int ls = l0 + s * SL;
        float4v acc1[8];
#pragma unroll
        for (int nt = 0; nt < 8; ++nt) acc1[nt] = (float4v){0.f, 0.f, 0.f, 0.f};
        const int l = ls + w * 16 + ra;
#pragma unroll
        for (int kt = 0; kt < 4; ++kt) {
            const float* qp = queries + ((size_t)(b * D_ + kt * 32 + qa * 8)) * L_ + l;
            ushort8 a;
#pragma unroll
            for (int j = 0; j < 8; ++j) a[j] = f2bf(qp[(size_t)j * L_]);
#pragma unroll
            for (int nt = 0; nt < 8; ++nt)
                acc1[nt] = mfma16(a, *(const ushort8*)(FB + ((kt * 8 + nt) * 64 + lane) * 8),
                                  acc1[nt]);
        }
        const int qc = qa, cc = ra;
        ushort_t* pp = phi_q + ((size_t)(b * L_ + ls + w * 16 + qc * 4)) * M_;
#pragma unroll
        for (int nt = 0; nt < 8; ++nt) {
            float4v p = acc1[nt];
            int col = nt * 16 + cc;
            pp[0 * M_ + col] = f2bf(fmaxf(p.x, 0.f) * PHI_SCALE);
            pp[1 * M_ + col] = f2bf(fmaxf(p.y, 0.f) * PHI_SCALE);
            pp[2 * M_ + col] = f2bf(fmaxf(p.z, 0.f) * PHI_SCALE);
            pp[3 * M_ + col] = f2bf(fmaxf(p.w, 0.f) * PHI_SCALE);
        }
    }
}

// Kernel R: reduce 16 chunk-partials -> kv_ext (128 x 144, col128 = ksum) as bf16 in
// B-frag layout blocks [kt 0..3][nt 0..8][lane64][j]; one thread per 16B slot.
__global__ __launch_bounds__(256) void kernelR(const float* __restrict__ kvp,
                                               const float* __restrict__ ksum_p,
                                               ushort_t* __restrict__ kv_final) {
    int t = blockIdx.x * 256 + threadIdx.x;  // 0..36863
    int b = t / 2304, bid = t % 2304;
    int cb = bid & 15, qb = (bid >> 4) & 3, rest = bid >> 6;
    int nt = rest % 9, kt = rest / 9;
    ushort8 u = {0, 0, 0, 0, 0, 0, 0, 0};
    if (nt < 8) {
        int v = nt * 16 + cb;
#pragma unroll
        for (int j = 0; j < 8; ++j) {
            int m = kt * 32 + qb * 8 + j;
            float sum = 0.f;
            for (int c = 0; c < 16; ++c)
                sum += kvp[(((size_t)b * NCHUNK + c) * M_ + m) * D_ + v];
            u[j] = f2bf(sum);
        }
    } else if (cb == 0) {  // col 128 = ksum
#pragma unroll
        for (int j = 0; j < 8; ++j) {
            int m = kt * 32 + qb * 8 + j;
            float sum = 0.f;
            for (int c = 0; c < 16; ++c)
                for (int w2 = 0; w2 < 4; ++w2)
                    sum += ksum_p[((size_t)(b * NCHUNK + c) * 4 + w2) * M_ + m];
            u[j] = f2bf(sum);
        }
    }
    *(ushort8*)(kv_final + (size_t)t * 8) = u;
}

// Kernel C: out[l][v] = (phi_q @ kv_ext)/denom ; denom from n-tile 8 (ksum column)
__global__ __launch_bounds__(256) void kernelC(const ushort_t* __restrict__ phi_q,
                                               const ushort_t* __restrict__ kv_final,
                                               float* __restrict__ out) {
    __shared__ ushort_t KVB[18432];  // 36 KB
    const int tid = threadIdx.x;
    const int chunk = blockIdx.x, b = blockIdx.y;
#pragma unroll
    for (int it = 0; it < 9; ++it) {
        int bid = tid + it * 256;  // 0..2303
        *(ushort8*)(KVB + bid * 8) =
            *(const ushort8*)(kv_final + ((size_t)b * 2304 + bid) * 8);
    }
    __syncthreads();

    const int w = tid >> 6, lane = tid & 63;
    const int qa = lane >> 4, ra = lane & 15;

    for (int s = 0; s < 8; ++s) {
        const int ls = chunk * LT + s * SL;
        const int l = ls + w * 16 + ra;
        float4v acc[9];
#pragma unroll
        for (int nt = 0; nt < 9; ++nt) acc[nt] = (float4v){0.f, 0.f, 0.f, 0.f};
#pragma unroll
        for (int kt = 0; kt < 4; ++kt) {
            ushort8 a = *(const ushort8*)(phi_q + ((size_t)(b * L_ + l)) * M_ + kt * 32 + qa * 8);
#pragma unroll
            for (int nt = 0; nt < 9; ++nt)
                acc[nt] = mfma16(a, *(const ushort8*)(KVB + ((kt * 9 + nt) * 64 + lane) * 8),
                                 acc[nt]);
        }
        // denom lives in tile nt=8, column 128 (cc==0); broadcast within row-group
        float4v dv = acc[8];
        int src = lane & 48;
        float i0 = 1.0f / __shfl(dv.x, src);
        float i1 = 1.0f / __shfl(dv.y, src);
        float i2 = 1.0f / __shfl(dv.z, src);
        float i3 = 1.0f / __shfl(dv.w, src);
        const int qc = qa, cc = ra;
        const int lbase = ls + w * 16 + qc * 4;
#pragma unroll
        for (int nt = 0; nt < 8; ++nt) {
            float4v o = acc[nt];
            o.x *= i0; o.y *= i1; o.z *= i2; o.w *= i3;
            *(float4v*)(out + ((size_t)(b * D_ + nt * 16 + cc)) * L_ + lbase) = o;
        }
    }
}

extern "C" void kernel_launch(void* const* d_in, const int* in_sizes, int n_in,
                              void* d_out, int out_size, void* d_ws, size_t ws_size,
                              hipStream_t stream) {
    (void)in_sizes; (void)n_in; (void)out_size; (void)ws_size;
    const float* keys     = (const float*)d_in[0];
    const float* values   = (const float*)d_in[1];
    const float* queries  = (const float*)d_in[2];
    const float* features = (const float*)d_in[3];
    float* out = (float*)d_out;

    // workspace partition (total ~51.4 MB)
    char* ws = (char*)d_ws;
    ushort_t* phi_q   = (ushort_t*)ws;                                   // 16*8192*128*2  = 33,554,432
    float*    kvp     = (float*)(ws + 33554432);                         // 16*16*128*128*4= 16,777,216
    float*    ksum_p  = (float*)(ws + 33554432 + 16777216);              // 16*16*4*128*4  =    524,288
    ushort_t* kv_final= (ushort_t*)(ws + 33554432 + 16777216 + 524288);  // 16*2304*8*2    =    589,824

    dim3 grid(NCHUNK, B_);
    kernelA<<<grid, 256, 0, stream>>>(keys, values, features, kvp, ksum_p);
    kernelQ<<<grid, 256, 0, stream>>>(queries, features, phi_q);
    kernelR<<<144, 256, 0, stream>>>(kvp, ksum_p, kv_final);
    kernelC<<<grid, 256, 0, stream>>>(phi_q, kv_final, out);
}